// Round 4
// baseline (4165.008 us; speedup 1.0000x reference)
//
#include <hip/hip_runtime.h>

// vol[n,d,h,w] = sum_c L[n,c,h,w] * R[n,c,h,w-d], 0 if w<d
// N=4, C=128, H=160, W=320, D=48, fp32 in/out.
//
// 1280 blocks = (n,h) rows x 2 w-halves -> 5 blocks/CU. Pipeline per 16-channel
// chunk: global loads -> REGISTERS (issued before compute, consumed after) ->
// pack half2 -> ds_write other LDS buffer -> barrier. This keeps compute free
// of vmcnt dependencies so HBM latency hides under dot2 work.

#define NN 4
#define CC 128
#define HH 160
#define WW 320
#define DD 48
#define HWs (HH * WW)
#define WB 160   // w extent per block
#define RJ 208   // staged R extent in h2 (j in [wb-48, wb+160))
#define NTASK 736  // 320 L float4-pair tasks + 416 R tasks

typedef _Float16 h2 __attribute__((ext_vector_type(2)));
typedef __fp16 h2raw __attribute__((ext_vector_type(2)));

union V4 { float4 f; h2 h[4]; };

__device__ __forceinline__ h2 pack2(float a, float b) {
  union { h2raw r; h2 h; } u;
  u.r = __builtin_amdgcn_cvt_pkrtz(a, b);  // v_cvt_pkrtz_f16_f32
  return u.h;
}

__device__ __forceinline__ float dot2(h2 a, h2 b, float c) {
  return __builtin_amdgcn_fdot2(a, b, c, false);  // v_dot2_f32_f16
}

__global__ __launch_bounds__(256, 5)
void corr_kernel(const float* __restrict__ L, const float* __restrict__ R,
                 float* __restrict__ out) {
  __shared__ __align__(16) h2 Lsp[2][8][WB];  // 10.0 KB
  __shared__ __align__(16) h2 Rsp[2][8][RJ];  // 13.0 KB

  const int tid = threadIdx.x;
  const int wg = tid & 31;   // 32 w-groups x 5 w
  const int jg = tid >> 5;   // 8 j-groups x 8 j
  const int bid = blockIdx.x;
  const int wsplit = bid & 1;
  const int row = bid >> 1;
  const int n = row / HH;
  const int h = row - n * HH;
  const int wb = wsplit * WB;

  const int u0 = 5 * wg;                  // w = wb + u0 + i
  int S = (u0 + 1) & ~7;                  // 8-aligned 64-j window start
  if (S > RJ - 64) S = RJ - 64;
  const int js0 = S + 8 * jg;             // this thread's 8-j slice

  const size_t base = (size_t)n * CC * HWs + (size_t)h * WW;
  const float* Lb = L + base + wb;
  const float* Rb = R + base + (wb - 48);  // Rb[js] = R[..., wb-48+js]

  // ---- precompute staging tasks (<=3 per thread), chunk-invariant parts ----
  const float* gptr[3];
  h2* dst0[3];
  int dstride[3];
  bool act[3], val[3];
#pragma unroll
  for (int s = 0; s < 3; ++s) {
    const int t = tid + 256 * s;
    act[s] = (t < NTASK);
    val[s] = false;
    gptr[s] = Lb;
    dst0[s] = &Lsp[0][0][0];
    dstride[s] = 0;
    if (act[s]) {
      if (t < 320) {                       // L task: 8 cp x 40 float4-pos
        const int cp = t / 40, v = t - cp * 40;
        gptr[s] = Lb + (size_t)(2 * cp) * HWs + 4 * v;
        dst0[s] = &Lsp[0][cp][4 * v];
        dstride[s] = 8 * WB;
        val[s] = true;
      } else {                             // R task: 8 cp x 52 float4-pos
        const int u = t - 320;
        const int cp = u / 52, v = u - cp * 52;
        val[s] = (wb - 48 + 4 * v) >= 0;   // float4 fully valid or fully pad
        gptr[s] = Rb + (size_t)(2 * cp) * HWs + 4 * v;
        dst0[s] = &Rsp[0][cp][4 * v];
        dstride[s] = 8 * RJ;
      }
    }
  }

  float4 pa[3], pc[3];

  auto prefetch = [&](int q) {
    const size_t coff = (size_t)(16 * q) * HWs;
#pragma unroll
    for (int s = 0; s < 3; ++s) {
      pa[s] = make_float4(0.f, 0.f, 0.f, 0.f);
      pc[s] = make_float4(0.f, 0.f, 0.f, 0.f);
      if (act[s] && val[s]) {
        pa[s] = *(const float4*)(gptr[s] + coff);
        pc[s] = *(const float4*)(gptr[s] + coff + HWs);
      }
    }
  };

  auto writeback = [&](int b) {
#pragma unroll
    for (int s = 0; s < 3; ++s) {
      if (act[s]) {
        V4 u;
        u.h[0] = pack2(pa[s].x, pc[s].x);
        u.h[1] = pack2(pa[s].y, pc[s].y);
        u.h[2] = pack2(pa[s].z, pc[s].z);
        u.h[3] = pack2(pa[s].w, pc[s].w);
        *(float4*)(dst0[s] + (size_t)b * dstride[s]) = u.f;
      }
    }
  };

  float acc[5][8];
#pragma unroll
  for (int i = 0; i < 5; ++i)
#pragma unroll
    for (int k = 0; k < 8; ++k) acc[i][k] = 0.f;

  auto compute = [&](int b) {
#pragma unroll
    for (int cpl = 0; cpl < 8; ++cpl) {
      h2 lv[5];
#pragma unroll
      for (int i = 0; i < 5; ++i) lv[i] = Lsp[b][cpl][u0 + i];
      V4 r0, r1;
      r0.f = *(const float4*)&Rsp[b][cpl][js0];
      r1.f = *(const float4*)&Rsp[b][cpl][js0 + 4];
      h2 rv[8] = {r0.h[0], r0.h[1], r0.h[2], r0.h[3],
                  r1.h[0], r1.h[1], r1.h[2], r1.h[3]};
#pragma unroll
      for (int i = 0; i < 5; ++i)
#pragma unroll
        for (int k = 0; k < 8; ++k)
          acc[i][k] = dot2(lv[i], rv[k], acc[i][k]);
    }
  };

  // ---- software pipeline: loads(q+1) || compute(q), one barrier/iter ----
  prefetch(0);
  writeback(0);
  __syncthreads();
#pragma unroll
  for (int q = 0; q < 8; ++q) {
    const int b = q & 1;
    if (q < 7) prefetch(q + 1);   // global loads in flight during compute
    compute(b);
    if (q < 7) {
      writeback(b ^ 1);           // vmcnt wait lands here, after compute
      __syncthreads();
    }
  }

  // ---- epilogue: d = w - j = u0+i+48-(js0+k); store valid entries ----
  float* ob = out + (size_t)n * DD * HWs + (size_t)h * WW + wb + u0;
#pragma unroll
  for (int i = 0; i < 5; ++i)
#pragma unroll
    for (int k = 0; k < 8; ++k) {
      const int d = u0 + i + 48 - (js0 + k);
      if (d >= 0 && d < DD) ob[(size_t)d * HWs + i] = acc[i][k];
    }
}

extern "C" void kernel_launch(void* const* d_in, const int* in_sizes, int n_in,
                              void* d_out, int out_size, void* d_ws, size_t ws_size,
                              hipStream_t stream) {
  const float* L = (const float*)d_in[0];
  const float* R = (const float*)d_in[1];
  float* out = (float*)d_out;
  corr_kernel<<<dim3(2 * NN * HH), dim3(256), 0, stream>>>(L, R, out);
}

// Round 5
// 3831.166 us; speedup vs baseline: 1.0871x; 1.0871x over previous
//
#include <hip/hip_runtime.h>

// vol[n,d,h,w] = sum_c L[n,c,h,w] * R[n,c,h,w-d], 0 if w<d
// N=4, C=128, H=160, W=320, D=48, fp32 in/out.
//
// 1280 blocks = (n,h) rows x 2 w-halves. Register-prefetch pipeline per
// 16-channel chunk: global float4 loads -> named scalar regs (issued before
// compute) -> compute(q) from LDS -> pack half2 -> ds_write other buffer ->
// barrier. NO local arrays / lambdas (R4 post-mortem: they went to scratch,
// 7.8 GB fetch). Scalars only.

#define NN 4
#define CC 128
#define HH 160
#define WW 320
#define DD 48
#define HWs (HH * WW)
#define WB 160            // w extent per block
#define RJ 208            // staged R extent in h2 (j in [wb-48, wb+160))
#define LSZ (8 * WB)      // 1280 h2: L region size per buffer
#define SSZ (8 * WB + 8 * RJ)  // 2944 h2 per buffer (11.5 KB)

typedef _Float16 h2 __attribute__((ext_vector_type(2)));
typedef __fp16 h2raw __attribute__((ext_vector_type(2)));

union V4 { float4 f; h2 h[4]; };

__device__ __forceinline__ h2 pack2(float a, float b) {
  union { h2raw r; h2 h; } u;
  u.r = __builtin_amdgcn_cvt_pkrtz(a, b);  // v_cvt_pkrtz_f16_f32
  return u.h;
}

__device__ __forceinline__ float dot2(h2 a, h2 b, float c) {
  return __builtin_amdgcn_fdot2(a, b, c, false);  // v_dot2_f32_f16
}

__global__ __launch_bounds__(256, 4)
void corr_kernel(const float* __restrict__ L, const float* __restrict__ R,
                 float* __restrict__ out) {
  __shared__ __align__(16) h2 SH[2][SSZ];  // 23 KB total

  const int tid = threadIdx.x;
  const int wg = tid & 31;   // 32 w-groups x 5 w
  const int jg = tid >> 5;   // 8 j-groups x 8 j
  const int bid = blockIdx.x;
  const int wsplit = bid & 1;
  const int row = bid >> 1;
  const int n = row / HH;
  const int h = row - n * HH;
  const int wb = wsplit * WB;

  const int u0 = 5 * wg;                  // w = wb + u0 + i
  int Swin = (u0 + 1) & ~7;               // 8-aligned 64-j window start
  if (Swin > RJ - 64) Swin = RJ - 64;
  const int js0 = Swin + 8 * jg;          // this thread's 8-j slice

  const size_t base = (size_t)n * CC * HWs + (size_t)h * WW;
  const float* Lb = L + base + wb;
  const float* Rb = R + base + (wb - 48);  // Rb[js] = R[..., wb-48+js]

  // ---- staging tasks: 320 L float4-pairs + 416 R float4-pairs = 736 ----
  // task0 = tid        -> always L (cp = t/40, v = t%40)
  // task1 = tid + 256  -> L if tid<64 else R (u = tid-64, cp = u/52, v = u%52)
  // task2 = tid + 512  -> R (u = tid+192), active iff tid<224
  const int cp0 = tid / 40, vv0 = tid - cp0 * 40;
  const float* g0 = Lb + (size_t)(2 * cp0) * HWs + 4 * vv0;
  const int d0 = cp0 * WB + 4 * vv0;

  const float* g1;
  int d1;
  bool val1;
  if (tid < 64) {
    const int t = tid + 256;
    const int cp = t / 40, v = t - cp * 40;
    g1 = Lb + (size_t)(2 * cp) * HWs + 4 * v;
    d1 = cp * WB + 4 * v;
    val1 = true;
  } else {
    const int u = tid - 64;
    const int cp = u / 52, v = u - cp * 52;
    g1 = Rb + (size_t)(2 * cp) * HWs + 4 * v;
    d1 = LSZ + cp * RJ + 4 * v;
    val1 = (wb - 48 + 4 * v) >= 0;  // float4 fully valid or fully pad
  }

  const bool act2 = (tid < 224);
  const int u2 = tid + 192;
  const int cp2r = (u2 / 52) & 7;  // mask keeps inactive threads in-bounds
  const int vv2 = u2 - (u2 / 52) * 52;
  const float* g2 = Rb + (size_t)(2 * cp2r) * HWs + 4 * vv2;
  const int d2 = LSZ + cp2r * RJ + 4 * vv2;
  const bool val2 = act2 && ((wb - 48 + 4 * vv2) >= 0);

  float4 a0, c0, a1, c1, a2, c2;

#define PREFETCH(Q) {                                                   \
    const size_t coff = (size_t)(16 * (Q)) * HWs;                       \
    a0 = *(const float4*)(g0 + coff);                                   \
    c0 = *(const float4*)(g0 + coff + HWs);                             \
    a1 = make_float4(0.f, 0.f, 0.f, 0.f); c1 = a1;                      \
    if (val1) { a1 = *(const float4*)(g1 + coff);                       \
                c1 = *(const float4*)(g1 + coff + HWs); }               \
    a2 = make_float4(0.f, 0.f, 0.f, 0.f); c2 = a2;                      \
    if (val2) { a2 = *(const float4*)(g2 + coff);                       \
                c2 = *(const float4*)(g2 + coff + HWs); }               \
  }

#define WRITEBACK(B) {                                                  \
    V4 u;                                                               \
    u.h[0] = pack2(a0.x, c0.x); u.h[1] = pack2(a0.y, c0.y);             \
    u.h[2] = pack2(a0.z, c0.z); u.h[3] = pack2(a0.w, c0.w);             \
    *(float4*)&SH[B][d0] = u.f;                                         \
    u.h[0] = pack2(a1.x, c1.x); u.h[1] = pack2(a1.y, c1.y);             \
    u.h[2] = pack2(a1.z, c1.z); u.h[3] = pack2(a1.w, c1.w);             \
    *(float4*)&SH[B][d1] = u.f;                                         \
    if (act2) {                                                         \
      u.h[0] = pack2(a2.x, c2.x); u.h[1] = pack2(a2.y, c2.y);           \
      u.h[2] = pack2(a2.z, c2.z); u.h[3] = pack2(a2.w, c2.w);           \
      *(float4*)&SH[B][d2] = u.f;                                       \
    }                                                                   \
  }

  float acc[5][8];
#pragma unroll
  for (int i = 0; i < 5; ++i)
#pragma unroll
    for (int k = 0; k < 8; ++k) acc[i][k] = 0.f;

#define COMPUTE(B) {                                                    \
    _Pragma("unroll")                                                   \
    for (int cpl = 0; cpl < 8; ++cpl) {                                 \
      h2 lv[5];                                                         \
      _Pragma("unroll")                                                 \
      for (int i = 0; i < 5; ++i) lv[i] = SH[B][cpl * WB + u0 + i];     \
      V4 r0, r1;                                                        \
      r0.f = *(const float4*)&SH[B][LSZ + cpl * RJ + js0];              \
      r1.f = *(const float4*)&SH[B][LSZ + cpl * RJ + js0 + 4];          \
      h2 rv[8] = {r0.h[0], r0.h[1], r0.h[2], r0.h[3],                   \
                  r1.h[0], r1.h[1], r1.h[2], r1.h[3]};                  \
      _Pragma("unroll")                                                 \
      for (int i = 0; i < 5; ++i)                                       \
        _Pragma("unroll")                                               \
        for (int k = 0; k < 8; ++k)                                     \
          acc[i][k] = dot2(lv[i], rv[k], acc[i][k]);                    \
    }                                                                   \
  }

  // ---- pipeline: loads(q+1) in flight during compute(q), 1 barrier/iter ----
  PREFETCH(0)
  WRITEBACK(0)
  __syncthreads();
#pragma unroll
  for (int q = 0; q < 8; ++q) {
    const int b = q & 1;
    if (q < 7) PREFETCH(q + 1)
    COMPUTE(b)
    if (q < 7) {
      WRITEBACK(b ^ 1)   // vmcnt wait lands here, after compute
      __syncthreads();
    }
  }

  // ---- epilogue: d = w - j = u0+i+48-(js0+k); store valid entries ----
  float* ob = out + (size_t)n * DD * HWs + (size_t)h * WW + wb + u0;
#pragma unroll
  for (int i = 0; i < 5; ++i)
#pragma unroll
    for (int k = 0; k < 8; ++k) {
      const int d = u0 + i + 48 - (js0 + k);
      if (d >= 0 && d < DD) ob[(size_t)d * HWs + i] = acc[i][k];
    }
}

extern "C" void kernel_launch(void* const* d_in, const int* in_sizes, int n_in,
                              void* d_out, int out_size, void* d_ws, size_t ws_size,
                              hipStream_t stream) {
  const float* L = (const float*)d_in[0];
  const float* R = (const float*)d_in[1];
  float* out = (float*)d_out;
  corr_kernel<<<dim3(2 * NN * HH), dim3(256), 0, stream>>>(L, R, out);
}